// Round 1
// baseline (1076.528 us; speedup 1.0000x reference)
//
#include <hip/hip_runtime.h>
#include <cstddef>

#define DIMC 128
#define BN_EPS 1e-5f

// ---------------------------------------------------------------------------
// Kernel 1: scatter-mean accumulation. One wave (64 lanes) per edge; each lane
// handles 2 of the 128 dims via float2. Counts accumulated by lane 0.
// ---------------------------------------------------------------------------
__global__ void scatter_add_kernel(const float* __restrict__ edge_attr,
                                   const int* __restrict__ src,
                                   float* __restrict__ sums,
                                   float* __restrict__ cnt,
                                   int nE) {
  const int gtid = blockIdx.x * blockDim.x + threadIdx.x;
  const int wave = gtid >> 6;
  const int lane = threadIdx.x & 63;
  const int nw = (gridDim.x * blockDim.x) >> 6;
  for (int e = wave; e < nE; e += nw) {
    const int s = src[e];
    const float2 v =
        *reinterpret_cast<const float2*>(edge_attr + (size_t)e * DIMC + lane * 2);
    float* dst = sums + (size_t)s * DIMC + lane * 2;
    atomicAdd(dst + 0, v.x);
    atomicAdd(dst + 1, v.y);
    if (lane == 0) atomicAdd(cnt + s, 1.0f);
  }
}

// ---------------------------------------------------------------------------
// Kernel 2: tiled fp32 GEMM  H = relu(A' @ W^T + b), fused BN-stat reduction.
//   MODE 0: A'[i,k] = k<128 ? x[i,k] : k<256 ? sums[i,k-128]/max(cnt,1)
//                                    : u[batch[i], k-256]         (KTOT=384)
//   MODE 1: A'[i,k] = in_scale[k]*A[i,k] + in_shift[k]            (KTOT=128)
// Tile: 64 rows x 128 cols, BK=32. 256 threads, each 8 rows x 4 cols.
// Also accumulates per-column sum and sum-of-squares of the relu output into
// stats[0..127] / stats[128..255] via block-level LDS reduce + atomics.
// ---------------------------------------------------------------------------
#define BM 64
#define BK 32

template <int KTOT, int MODE>
__launch_bounds__(256)
__global__ void gemm_bn_kernel(const float* __restrict__ A,
                               const float* __restrict__ sums,
                               const float* __restrict__ cnt,
                               const float* __restrict__ u,
                               const int* __restrict__ batch,
                               const float* __restrict__ in_scale,
                               const float* __restrict__ in_shift,
                               const float* __restrict__ W,     // [128][KTOT]
                               const float* __restrict__ bias,  // [128]
                               float* __restrict__ H,           // [N][128]
                               float* __restrict__ stats,       // [2*128]
                               int N) {
  __shared__ float As[BM][BK + 4];     // +4 keeps rows 16B-aligned
  __shared__ float Ws[BK][DIMC + 4];
  __shared__ float red[8][DIMC];

  const int t = threadIdx.x;
  const int row0 = blockIdx.x * BM;
  const int colb = (t & 31) * 4;  // 0..124
  const int rowb = (t >> 5) * 8;  // 0..56

  float acc[8][4];
#pragma unroll
  for (int i = 0; i < 8; ++i)
#pragma unroll
    for (int j = 0; j < 4; ++j) acc[i][j] = 0.f;

  for (int k0 = 0; k0 < KTOT; k0 += BK) {
    // ---- stage A tile: 64 rows x 32 k = 512 float4, 2 per thread ----
#pragma unroll
    for (int it = 0; it < 2; ++it) {
      const int idx = t + it * 256;  // 0..511
      const int r = idx >> 3;
      const int kq = idx & 7;
      int grow = row0 + r;
      if (grow >= N) grow = N - 1;
      const int k = k0 + kq * 4;
      float4 v;
      if constexpr (MODE == 0) {
        if (k < 128) {
          v = *reinterpret_cast<const float4*>(A + (size_t)grow * DIMC + k);
        } else if (k < 256) {
          const float ic = 1.0f / fmaxf(cnt[grow], 1.0f);
          float4 s =
              *reinterpret_cast<const float4*>(sums + (size_t)grow * DIMC + (k - 128));
          v = make_float4(s.x * ic, s.y * ic, s.z * ic, s.w * ic);
        } else {
          const int g = batch[grow];
          v = *reinterpret_cast<const float4*>(u + (size_t)g * DIMC + (k - 256));
        }
      } else {
        float4 h4 = *reinterpret_cast<const float4*>(A + (size_t)grow * DIMC + k);
        float4 sc = *reinterpret_cast<const float4*>(in_scale + k);
        float4 sh = *reinterpret_cast<const float4*>(in_shift + k);
        v = make_float4(h4.x * sc.x + sh.x, h4.y * sc.y + sh.y,
                        h4.z * sc.z + sh.z, h4.w * sc.w + sh.w);
      }
      *reinterpret_cast<float4*>(&As[r][kq * 4]) = v;
    }
    // ---- stage W tile: 128 cols x 32 k, transposed to [k][col] ----
#pragma unroll
    for (int it = 0; it < 4; ++it) {
      const int idx = t + it * 256;  // float4 idx 0..1023
      const int c = idx >> 3;
      const int kq = idx & 7;
      float4 v = *reinterpret_cast<const float4*>(W + (size_t)c * KTOT + k0 + kq * 4);
      Ws[kq * 4 + 0][c] = v.x;
      Ws[kq * 4 + 1][c] = v.y;
      Ws[kq * 4 + 2][c] = v.z;
      Ws[kq * 4 + 3][c] = v.w;
    }
    __syncthreads();
    // ---- compute ----
#pragma unroll
    for (int kk0 = 0; kk0 < BK; kk0 += 4) {
      float4 a4[8];
#pragma unroll
      for (int rr = 0; rr < 8; ++rr)
        a4[rr] = *reinterpret_cast<const float4*>(&As[rowb + rr][kk0]);
#pragma unroll
      for (int q = 0; q < 4; ++q) {
        const float4 b4 = *reinterpret_cast<const float4*>(&Ws[kk0 + q][colb]);
#pragma unroll
        for (int rr = 0; rr < 8; ++rr) {
          const float av = (q == 0) ? a4[rr].x
                         : (q == 1) ? a4[rr].y
                         : (q == 2) ? a4[rr].z
                                    : a4[rr].w;
          acc[rr][0] += av * b4.x;
          acc[rr][1] += av * b4.y;
          acc[rr][2] += av * b4.z;
          acc[rr][3] += av * b4.w;
        }
      }
    }
    __syncthreads();
  }

  // ---- epilogue: bias + relu + store + fused BN stats ----
  const float4 b4 = *reinterpret_cast<const float4*>(bias + colb);
  float s1[4] = {0.f, 0.f, 0.f, 0.f};
  float s2[4] = {0.f, 0.f, 0.f, 0.f};
#pragma unroll
  for (int rr = 0; rr < 8; ++rr) {
    const int grow = row0 + rowb + rr;
    const float v0 = fmaxf(acc[rr][0] + b4.x, 0.f);
    const float v1 = fmaxf(acc[rr][1] + b4.y, 0.f);
    const float v2 = fmaxf(acc[rr][2] + b4.z, 0.f);
    const float v3 = fmaxf(acc[rr][3] + b4.w, 0.f);
    if (grow < N) {
      *reinterpret_cast<float4*>(H + (size_t)grow * DIMC + colb) =
          make_float4(v0, v1, v2, v3);
      s1[0] += v0; s1[1] += v1; s1[2] += v2; s1[3] += v3;
      s2[0] += v0 * v0; s2[1] += v1 * v1; s2[2] += v2 * v2; s2[3] += v3 * v3;
    }
  }
  const int ty = t >> 5;
#pragma unroll
  for (int cc = 0; cc < 4; ++cc) red[ty][colb + cc] = s1[cc];
  __syncthreads();
  if (t < DIMC) {
    float s = 0.f;
#pragma unroll
    for (int r = 0; r < 8; ++r) s += red[r][t];
    atomicAdd(&stats[t], s);
  }
  __syncthreads();
#pragma unroll
  for (int cc = 0; cc < 4; ++cc) red[ty][colb + cc] = s2[cc];
  __syncthreads();
  if (t < DIMC) {
    float s = 0.f;
#pragma unroll
    for (int r = 0; r < 8; ++r) s += red[r][t];
    atomicAdd(&stats[DIMC + t], s);
  }
}

// ---------------------------------------------------------------------------
// Kernel 3: finalize BN stats -> per-column scale/shift
// ---------------------------------------------------------------------------
__global__ void finalize_stats_kernel(const float* __restrict__ stats,
                                      const float* __restrict__ g,
                                      const float* __restrict__ beta,
                                      float* __restrict__ scale,
                                      float* __restrict__ shift, float invN) {
  const int c = threadIdx.x;
  const float m = stats[c] * invN;
  float v = stats[DIMC + c] * invN - m * m;
  v = fmaxf(v, 0.f);
  const float sc = g[c] * rsqrtf(v + BN_EPS);
  scale[c] = sc;
  shift[c] = beta[c] - m * sc;
}

// ---------------------------------------------------------------------------
// Kernel 4: final elementwise affine (apply BN of layer 2) into d_out
// ---------------------------------------------------------------------------
__global__ void final_affine_kernel(const float* __restrict__ h,
                                    const float* __restrict__ scale,
                                    const float* __restrict__ shift,
                                    float* __restrict__ out, int nvec4) {
  const int start = blockIdx.x * blockDim.x + threadIdx.x;
  const int stride = gridDim.x * blockDim.x;
  for (int i = start; i < nvec4; i += stride) {
    const int c = (i & 31) * 4;  // column within 128-wide row
    float4 hv = reinterpret_cast<const float4*>(h)[i];
    float4 sc = *reinterpret_cast<const float4*>(scale + c);
    float4 sh = *reinterpret_cast<const float4*>(shift + c);
    reinterpret_cast<float4*>(out)[i] =
        make_float4(hv.x * sc.x + sh.x, hv.y * sc.y + sh.y, hv.z * sc.z + sh.z,
                    hv.w * sc.w + sh.w);
  }
}

// ---------------------------------------------------------------------------
extern "C" void kernel_launch(void* const* d_in, const int* in_sizes, int n_in,
                              void* d_out, int out_size, void* d_ws,
                              size_t ws_size, hipStream_t stream) {
  const float* x = (const float*)d_in[0];
  const int* edge_index = (const int*)d_in[1];  // [2][E]; row 0 = src
  const float* edge_attr = (const float*)d_in[2];
  const float* u = (const float*)d_in[3];
  const int* batch = (const int*)d_in[4];
  const float* W0 = (const float*)d_in[5];
  const float* b0 = (const float*)d_in[6];
  const float* W1 = (const float*)d_in[7];
  const float* b1 = (const float*)d_in[8];
  const float* W2 = (const float*)d_in[9];
  const float* b2 = (const float*)d_in[10];
  const float* g0 = (const float*)d_in[11];
  const float* be0 = (const float*)d_in[12];
  const float* g1 = (const float*)d_in[13];
  const float* be1 = (const float*)d_in[14];
  const float* g2 = (const float*)d_in[15];
  const float* be2 = (const float*)d_in[16];

  const int N = in_sizes[0] / DIMC;   // 50000
  const int E = in_sizes[2] / DIMC;   // 600000

  // Workspace layout (ping-pong the two 25.6MB regions):
  //   regionA: sums (scatter)  -> h1 (gemm1 out)
  //   regionB: h0 (gemm0 out)  -> h2 (gemm2 out)
  float* regionA = (float*)d_ws;
  float* cntp = regionA + (size_t)N * DIMC;
  float* regionB = cntp + N;
  float* stats = regionB + (size_t)N * DIMC;  // 6*128 floats (3 stages x 2)
  float* scsh = stats + 6 * DIMC;             // 6*128 floats

  float* sums = regionA;
  float* h0 = regionB;
  float* h1 = regionA;
  float* h2 = regionB;

  // zero accumulators (ws is poisoned before every launch)
  hipMemsetAsync(sums, 0, ((size_t)N * DIMC + N) * sizeof(float), stream);
  hipMemsetAsync(stats, 0, 6 * DIMC * sizeof(float), stream);

  // 1) scatter-mean accumulation
  scatter_add_kernel<<<2048, 256, 0, stream>>>(edge_attr, edge_index, sums,
                                               cntp, E);

  const int gblocks = (N + BM - 1) / BM;
  const float invN = 1.0f / (float)N;

  // 2) layer 0: comb @ W0^T, relu, stats
  gemm_bn_kernel<3 * DIMC, 0><<<gblocks, 256, 0, stream>>>(
      x, sums, cntp, u, batch, nullptr, nullptr, W0, b0, h0, stats, N);
  finalize_stats_kernel<<<1, DIMC, 0, stream>>>(stats, g0, be0, scsh,
                                                scsh + DIMC, invN);

  // 3) layer 1 (BN0 fused into A-load)
  gemm_bn_kernel<DIMC, 1><<<gblocks, 256, 0, stream>>>(
      h0, nullptr, nullptr, nullptr, nullptr, scsh, scsh + DIMC, W1, b1, h1,
      stats + 2 * DIMC, N);
  finalize_stats_kernel<<<1, DIMC, 0, stream>>>(stats + 2 * DIMC, g1, be1,
                                                scsh + 2 * DIMC,
                                                scsh + 3 * DIMC, invN);

  // 4) layer 2 (BN1 fused into A-load)
  gemm_bn_kernel<DIMC, 1><<<gblocks, 256, 0, stream>>>(
      h1, nullptr, nullptr, nullptr, nullptr, scsh + 2 * DIMC,
      scsh + 3 * DIMC, W2, b2, h2, stats + 4 * DIMC, N);
  finalize_stats_kernel<<<1, DIMC, 0, stream>>>(stats + 4 * DIMC, g2, be2,
                                                scsh + 4 * DIMC,
                                                scsh + 5 * DIMC, invN);

  // 5) apply BN2 -> output
  final_affine_kernel<<<2048, 256, 0, stream>>>(
      h2, scsh + 4 * DIMC, scsh + 5 * DIMC, (float*)d_out, (N * DIMC) / 4);
}

// Round 2
// 749.220 us; speedup vs baseline: 1.4369x; 1.4369x over previous
//
#include <hip/hip_runtime.h>
#include <cstddef>

#define DIMC 128
#define BN_EPS 1e-5f

// ===========================================================================
// Scatter-mean replacement: CSR build (hist + scan + bucket) then gather-sum.
// No float atomics anywhere.
// ===========================================================================

// --- 1a: histogram of src indices -----------------------------------------
__global__ void hist_kernel(const int* __restrict__ src, int* __restrict__ cnt,
                            int E) {
  int i = blockIdx.x * blockDim.x + threadIdx.x;
  const int stride = gridDim.x * blockDim.x;
  for (; i < E; i += stride) atomicAdd(&cnt[src[i]], 1);
}

// --- 1b: scan pass A: per-block (256-elem) reduce -------------------------
__global__ void scan_pass_a(const int* __restrict__ cnt, int* __restrict__ bsums,
                            int N) {
  __shared__ int sh[256];
  const int t = threadIdx.x;
  const int idx = blockIdx.x * 256 + t;
  sh[t] = (idx < N) ? cnt[idx] : 0;
  __syncthreads();
  for (int off = 128; off > 0; off >>= 1) {
    if (t < off) sh[t] += sh[t + off];
    __syncthreads();
  }
  if (t == 0) bsums[blockIdx.x] = sh[0];
}

// --- 1c: scan pass B: exclusive scan of 256 block sums (one block) --------
__global__ void scan_pass_b(int* __restrict__ bsums) {
  __shared__ int sh[256];
  const int t = threadIdx.x;
  const int v = bsums[t];
  sh[t] = v;
  __syncthreads();
  for (int off = 1; off < 256; off <<= 1) {
    const int add = (t >= off) ? sh[t - off] : 0;
    __syncthreads();
    sh[t] += add;
    __syncthreads();
  }
  bsums[t] = sh[t] - v;  // exclusive
}

// --- 1d: scan pass C: per-block exclusive scan + offset; write offs+cursor -
__global__ void scan_pass_c(const int* __restrict__ cnt,
                            const int* __restrict__ bsums,
                            int* __restrict__ offs, int* __restrict__ cursor,
                            int N) {
  __shared__ int sh[256];
  const int t = threadIdx.x;
  const int idx = blockIdx.x * 256 + t;
  const int v = (idx < N) ? cnt[idx] : 0;
  sh[t] = v;
  __syncthreads();
  for (int off = 1; off < 256; off <<= 1) {
    const int add = (t >= off) ? sh[t - off] : 0;
    __syncthreads();
    sh[t] += add;
    __syncthreads();
  }
  if (idx < N) {
    const int excl = sh[t] - v + bsums[blockIdx.x];
    offs[idx] = excl;
    cursor[idx] = excl;
  }
}

// --- 1e: bucket-fill edge ids ---------------------------------------------
__global__ void bucket_kernel(const int* __restrict__ src,
                              int* __restrict__ cursor, int* __restrict__ elist,
                              int E) {
  int i = blockIdx.x * blockDim.x + threadIdx.x;
  const int stride = gridDim.x * blockDim.x;
  for (; i < E; i += stride) {
    const int s = src[i];
    const int p = atomicAdd(&cursor[s], 1);
    elist[p] = i;
  }
}

// --- 1f: gather-mean: one wave per node, lane owns 2 dims ------------------
__global__ void gather_mean_kernel(const float* __restrict__ edge_attr,
                                   const int* __restrict__ elist,
                                   const int* __restrict__ offs,
                                   const int* __restrict__ cnt,
                                   float* __restrict__ ve, int N) {
  const int wid = (blockIdx.x * blockDim.x + threadIdx.x) >> 6;
  const int lane = threadIdx.x & 63;
  if (wid >= N) return;
  const int start = offs[wid];
  const int c = cnt[wid];
  float ax = 0.f, ay = 0.f;
  int j = 0;
  for (; j + 1 < c; j += 2) {
    const int e0 = elist[start + j];
    const int e1 = elist[start + j + 1];
    const float2 a0 =
        *reinterpret_cast<const float2*>(edge_attr + (size_t)e0 * DIMC + lane * 2);
    const float2 a1 =
        *reinterpret_cast<const float2*>(edge_attr + (size_t)e1 * DIMC + lane * 2);
    ax += a0.x + a1.x;
    ay += a0.y + a1.y;
  }
  if (j < c) {
    const int e0 = elist[start + j];
    const float2 a0 =
        *reinterpret_cast<const float2*>(edge_attr + (size_t)e0 * DIMC + lane * 2);
    ax += a0.x;
    ay += a0.y;
  }
  const float inv = 1.0f / fmaxf((float)c, 1.0f);
  *reinterpret_cast<float2*>(ve + (size_t)wid * DIMC + lane * 2) =
      make_float2(ax * inv, ay * inv);
}

// ===========================================================================
// Kernel 2: tiled fp32 GEMM  H = relu(A' @ W^T + b), fused BN-stat reduction.
//   MODE 0: A'[i,k] = k<128 ? x[i,k] : k<256 ? ve[i,k-128] : u[batch[i],k-256]
//   MODE 1: A'[i,k] = in_scale[k]*A[i,k] + in_shift[k]            (KTOT=128)
// ===========================================================================
#define BM 64
#define BK 32

template <int KTOT, int MODE>
__launch_bounds__(256)
__global__ void gemm_bn_kernel(const float* __restrict__ A,
                               const float* __restrict__ ve,
                               const float* __restrict__ u,
                               const int* __restrict__ batch,
                               const float* __restrict__ in_scale,
                               const float* __restrict__ in_shift,
                               const float* __restrict__ W,     // [128][KTOT]
                               const float* __restrict__ bias,  // [128]
                               float* __restrict__ H,           // [N][128]
                               float* __restrict__ stats,       // [2*128]
                               int N) {
  __shared__ float As[BM][BK + 4];
  __shared__ float Ws[BK][DIMC + 4];
  __shared__ float red[8][DIMC];

  const int t = threadIdx.x;
  const int row0 = blockIdx.x * BM;
  const int colb = (t & 31) * 4;
  const int rowb = (t >> 5) * 8;

  float acc[8][4];
#pragma unroll
  for (int i = 0; i < 8; ++i)
#pragma unroll
    for (int j = 0; j < 4; ++j) acc[i][j] = 0.f;

  for (int k0 = 0; k0 < KTOT; k0 += BK) {
#pragma unroll
    for (int it = 0; it < 2; ++it) {
      const int idx = t + it * 256;
      const int r = idx >> 3;
      const int kq = idx & 7;
      int grow = row0 + r;
      if (grow >= N) grow = N - 1;
      const int k = k0 + kq * 4;
      float4 v;
      if constexpr (MODE == 0) {
        if (k < 128) {
          v = *reinterpret_cast<const float4*>(A + (size_t)grow * DIMC + k);
        } else if (k < 256) {
          v = *reinterpret_cast<const float4*>(ve + (size_t)grow * DIMC + (k - 128));
        } else {
          const int g = batch[grow];
          v = *reinterpret_cast<const float4*>(u + (size_t)g * DIMC + (k - 256));
        }
      } else {
        float4 h4 = *reinterpret_cast<const float4*>(A + (size_t)grow * DIMC + k);
        float4 sc = *reinterpret_cast<const float4*>(in_scale + k);
        float4 sh = *reinterpret_cast<const float4*>(in_shift + k);
        v = make_float4(h4.x * sc.x + sh.x, h4.y * sc.y + sh.y,
                        h4.z * sc.z + sh.z, h4.w * sc.w + sh.w);
      }
      *reinterpret_cast<float4*>(&As[r][kq * 4]) = v;
    }
#pragma unroll
    for (int it = 0; it < 4; ++it) {
      const int idx = t + it * 256;
      const int c = idx >> 3;
      const int kq = idx & 7;
      float4 v = *reinterpret_cast<const float4*>(W + (size_t)c * KTOT + k0 + kq * 4);
      Ws[kq * 4 + 0][c] = v.x;
      Ws[kq * 4 + 1][c] = v.y;
      Ws[kq * 4 + 2][c] = v.z;
      Ws[kq * 4 + 3][c] = v.w;
    }
    __syncthreads();
#pragma unroll
    for (int kk0 = 0; kk0 < BK; kk0 += 4) {
      float4 a4[8];
#pragma unroll
      for (int rr = 0; rr < 8; ++rr)
        a4[rr] = *reinterpret_cast<const float4*>(&As[rowb + rr][kk0]);
#pragma unroll
      for (int q = 0; q < 4; ++q) {
        const float4 b4 = *reinterpret_cast<const float4*>(&Ws[kk0 + q][colb]);
#pragma unroll
        for (int rr = 0; rr < 8; ++rr) {
          const float av = (q == 0) ? a4[rr].x
                         : (q == 1) ? a4[rr].y
                         : (q == 2) ? a4[rr].z
                                    : a4[rr].w;
          acc[rr][0] += av * b4.x;
          acc[rr][1] += av * b4.y;
          acc[rr][2] += av * b4.z;
          acc[rr][3] += av * b4.w;
        }
      }
    }
    __syncthreads();
  }

  const float4 b4 = *reinterpret_cast<const float4*>(bias + colb);
  float s1[4] = {0.f, 0.f, 0.f, 0.f};
  float s2[4] = {0.f, 0.f, 0.f, 0.f};
#pragma unroll
  for (int rr = 0; rr < 8; ++rr) {
    const int grow = row0 + rowb + rr;
    const float v0 = fmaxf(acc[rr][0] + b4.x, 0.f);
    const float v1 = fmaxf(acc[rr][1] + b4.y, 0.f);
    const float v2 = fmaxf(acc[rr][2] + b4.z, 0.f);
    const float v3 = fmaxf(acc[rr][3] + b4.w, 0.f);
    if (grow < N) {
      *reinterpret_cast<float4*>(H + (size_t)grow * DIMC + colb) =
          make_float4(v0, v1, v2, v3);
      s1[0] += v0; s1[1] += v1; s1[2] += v2; s1[3] += v3;
      s2[0] += v0 * v0; s2[1] += v1 * v1; s2[2] += v2 * v2; s2[3] += v3 * v3;
    }
  }
  const int ty = t >> 5;
#pragma unroll
  for (int cc = 0; cc < 4; ++cc) red[ty][colb + cc] = s1[cc];
  __syncthreads();
  if (t < DIMC) {
    float s = 0.f;
#pragma unroll
    for (int r = 0; r < 8; ++r) s += red[r][t];
    atomicAdd(&stats[t], s);
  }
  __syncthreads();
#pragma unroll
  for (int cc = 0; cc < 4; ++cc) red[ty][colb + cc] = s2[cc];
  __syncthreads();
  if (t < DIMC) {
    float s = 0.f;
#pragma unroll
    for (int r = 0; r < 8; ++r) s += red[r][t];
    atomicAdd(&stats[DIMC + t], s);
  }
}

// --- finalize BN stats -> per-column scale/shift ---------------------------
__global__ void finalize_stats_kernel(const float* __restrict__ stats,
                                      const float* __restrict__ g,
                                      const float* __restrict__ beta,
                                      float* __restrict__ scale,
                                      float* __restrict__ shift, float invN) {
  const int c = threadIdx.x;
  const float m = stats[c] * invN;
  float v = stats[DIMC + c] * invN - m * m;
  v = fmaxf(v, 0.f);
  const float sc = g[c] * rsqrtf(v + BN_EPS);
  scale[c] = sc;
  shift[c] = beta[c] - m * sc;
}

// --- final elementwise affine (apply BN of layer 2) into d_out -------------
__global__ void final_affine_kernel(const float* __restrict__ h,
                                    const float* __restrict__ scale,
                                    const float* __restrict__ shift,
                                    float* __restrict__ out, int nvec4) {
  const int start = blockIdx.x * blockDim.x + threadIdx.x;
  const int stride = gridDim.x * blockDim.x;
  for (int i = start; i < nvec4; i += stride) {
    const int c = (i & 31) * 4;
    float4 hv = reinterpret_cast<const float4*>(h)[i];
    float4 sc = *reinterpret_cast<const float4*>(scale + c);
    float4 sh = *reinterpret_cast<const float4*>(shift + c);
    reinterpret_cast<float4*>(out)[i] =
        make_float4(hv.x * sc.x + sh.x, hv.y * sc.y + sh.y, hv.z * sc.z + sh.z,
                    hv.w * sc.w + sh.w);
  }
}

// ---------------------------------------------------------------------------
extern "C" void kernel_launch(void* const* d_in, const int* in_sizes, int n_in,
                              void* d_out, int out_size, void* d_ws,
                              size_t ws_size, hipStream_t stream) {
  const float* x = (const float*)d_in[0];
  const int* edge_index = (const int*)d_in[1];  // [2][E]; row 0 = src
  const float* edge_attr = (const float*)d_in[2];
  const float* u = (const float*)d_in[3];
  const int* batch = (const int*)d_in[4];
  const float* W0 = (const float*)d_in[5];
  const float* b0 = (const float*)d_in[6];
  const float* W1 = (const float*)d_in[7];
  const float* b1 = (const float*)d_in[8];
  const float* W2 = (const float*)d_in[9];
  const float* b2 = (const float*)d_in[10];
  const float* g0 = (const float*)d_in[11];
  const float* be0 = (const float*)d_in[12];
  const float* g1 = (const float*)d_in[13];
  const float* be1 = (const float*)d_in[14];
  const float* g2 = (const float*)d_in[15];
  const float* be2 = (const float*)d_in[16];

  const int N = in_sizes[0] / DIMC;   // 50000
  const int E = in_sizes[2] / DIMC;   // 600000
  const int SCAN_BLOCKS = 256;        // covers up to 65536 nodes

  // Workspace layout:
  //   regionA: ve (gather out)  -> h1 (gemm1 out)      [N*128 f]
  //   regionB: h0 (gemm0 out)   -> h2 (gemm2 out)      [N*128 f]
  //   cnt[N], offs[N+1], cursor[N], elist[E], bsums[256] (ints)
  //   stats[6*128], scsh[6*128] (floats)
  float* regionA = (float*)d_ws;
  float* regionB = regionA + (size_t)N * DIMC;
  int* cnt = (int*)(regionB + (size_t)N * DIMC);
  int* offs = cnt + N;
  int* cursor = offs + N + 1;
  int* elist = cursor + N;
  int* bsums = elist + E;
  float* stats = (float*)(bsums + SCAN_BLOCKS);
  float* scsh = stats + 6 * DIMC;

  float* ve = regionA;
  float* h0 = regionB;
  float* h1 = regionA;
  float* h2 = regionB;

  hipMemsetAsync(cnt, 0, N * sizeof(int), stream);
  hipMemsetAsync(stats, 0, 6 * DIMC * sizeof(float), stream);

  // 1) CSR build + gather-mean
  hist_kernel<<<512, 256, 0, stream>>>(edge_index, cnt, E);
  scan_pass_a<<<SCAN_BLOCKS, 256, 0, stream>>>(cnt, bsums, N);
  scan_pass_b<<<1, 256, 0, stream>>>(bsums);
  scan_pass_c<<<SCAN_BLOCKS, 256, 0, stream>>>(cnt, bsums, offs, cursor, N);
  bucket_kernel<<<512, 256, 0, stream>>>(edge_index, cursor, elist, E);
  gather_mean_kernel<<<(N * 64 + 255) / 256, 256, 0, stream>>>(
      edge_attr, elist, offs, cnt, ve, N);

  const int gblocks = (N + BM - 1) / BM;
  const float invN = 1.0f / (float)N;

  // 2) layer 0
  gemm_bn_kernel<3 * DIMC, 0><<<gblocks, 256, 0, stream>>>(
      x, ve, u, batch, nullptr, nullptr, W0, b0, h0, stats, N);
  finalize_stats_kernel<<<1, DIMC, 0, stream>>>(stats, g0, be0, scsh,
                                                scsh + DIMC, invN);

  // 3) layer 1 (BN0 fused into A-load)
  gemm_bn_kernel<DIMC, 1><<<gblocks, 256, 0, stream>>>(
      h0, nullptr, nullptr, nullptr, scsh, scsh + DIMC, W1, b1, h1,
      stats + 2 * DIMC, N);
  finalize_stats_kernel<<<1, DIMC, 0, stream>>>(stats + 2 * DIMC, g1, be1,
                                                scsh + 2 * DIMC,
                                                scsh + 3 * DIMC, invN);

  // 4) layer 2 (BN1 fused into A-load)
  gemm_bn_kernel<DIMC, 1><<<gblocks, 256, 0, stream>>>(
      h1, nullptr, nullptr, nullptr, scsh + 2 * DIMC, scsh + 3 * DIMC, W2, b2,
      h2, stats + 4 * DIMC, N);
  finalize_stats_kernel<<<1, DIMC, 0, stream>>>(stats + 4 * DIMC, g2, be2,
                                                scsh + 4 * DIMC,
                                                scsh + 5 * DIMC, invN);

  // 5) apply BN2 -> output
  final_affine_kernel<<<2048, 256, 0, stream>>>(
      h2, scsh + 4 * DIMC, scsh + 5 * DIMC, (float*)d_out, (N * DIMC) / 4);
}

// Round 3
// 663.668 us; speedup vs baseline: 1.6221x; 1.1289x over previous
//
#include <hip/hip_runtime.h>
#include <hip/hip_bf16.h>
#include <cstddef>
#include <cstdint>

#define DIMC 128
#define BN_EPS 1e-5f

typedef unsigned short u16;
typedef short bf16x8 __attribute__((ext_vector_type(8)));
typedef float f32x4 __attribute__((ext_vector_type(4)));

__device__ inline u16 f2bf(float f) {
  __hip_bfloat16 h = __float2bfloat16(f);
  return __builtin_bit_cast(u16, h);
}
__device__ inline float bf2f(u16 u) {
  __hip_bfloat16 h = __builtin_bit_cast(__hip_bfloat16, u);
  return __bfloat162float(h);
}
__device__ inline bf16x8 pack8(const float4& a, const float4& b) {
  bf16x8 v;
  v[0] = (short)f2bf(a.x); v[1] = (short)f2bf(a.y);
  v[2] = (short)f2bf(a.z); v[3] = (short)f2bf(a.w);
  v[4] = (short)f2bf(b.x); v[5] = (short)f2bf(b.y);
  v[6] = (short)f2bf(b.z); v[7] = (short)f2bf(b.w);
  return v;
}

// ===========================================================================
// CSR build (hist + scan + bucket) then gather-mean (bf16 output).
// ===========================================================================
__global__ void hist_kernel(const int* __restrict__ src, int* __restrict__ cnt,
                            int E) {
  int i = blockIdx.x * blockDim.x + threadIdx.x;
  const int stride = gridDim.x * blockDim.x;
  for (; i < E; i += stride) atomicAdd(&cnt[src[i]], 1);
}

__global__ void scan_pass_a(const int* __restrict__ cnt, int* __restrict__ bsums,
                            int N) {
  __shared__ int sh[256];
  const int t = threadIdx.x;
  const int idx = blockIdx.x * 256 + t;
  sh[t] = (idx < N) ? cnt[idx] : 0;
  __syncthreads();
  for (int off = 128; off > 0; off >>= 1) {
    if (t < off) sh[t] += sh[t + off];
    __syncthreads();
  }
  if (t == 0) bsums[blockIdx.x] = sh[0];
}

__global__ void scan_pass_b(int* __restrict__ bsums) {
  __shared__ int sh[256];
  const int t = threadIdx.x;
  const int v = bsums[t];
  sh[t] = v;
  __syncthreads();
  for (int off = 1; off < 256; off <<= 1) {
    const int add = (t >= off) ? sh[t - off] : 0;
    __syncthreads();
    sh[t] += add;
    __syncthreads();
  }
  bsums[t] = sh[t] - v;  // exclusive
}

__global__ void scan_pass_c(const int* __restrict__ cnt,
                            const int* __restrict__ bsums,
                            int* __restrict__ offs, int* __restrict__ cursor,
                            int N) {
  __shared__ int sh[256];
  const int t = threadIdx.x;
  const int idx = blockIdx.x * 256 + t;
  const int v = (idx < N) ? cnt[idx] : 0;
  sh[t] = v;
  __syncthreads();
  for (int off = 1; off < 256; off <<= 1) {
    const int add = (t >= off) ? sh[t - off] : 0;
    __syncthreads();
    sh[t] += add;
    __syncthreads();
  }
  if (idx < N) {
    const int excl = sh[t] - v + bsums[blockIdx.x];
    offs[idx] = excl;
    cursor[idx] = excl;
  }
}

__global__ void bucket_kernel(const int* __restrict__ src,
                              int* __restrict__ cursor, int* __restrict__ elist,
                              int E) {
  int i = blockIdx.x * blockDim.x + threadIdx.x;
  const int stride = gridDim.x * blockDim.x;
  for (; i < E; i += stride) {
    const int s = src[i];
    const int p = atomicAdd(&cursor[s], 1);
    elist[p] = i;
  }
}

// one wave per node; lane owns dims 2*lane, 2*lane+1; bf16 packed output
__global__ void gather_mean_kernel(const float* __restrict__ edge_attr,
                                   const int* __restrict__ elist,
                                   const int* __restrict__ offs,
                                   const int* __restrict__ cnt,
                                   u16* __restrict__ ve, int N) {
  const int wid = (blockIdx.x * blockDim.x + threadIdx.x) >> 6;
  const int lane = threadIdx.x & 63;
  if (wid >= N) return;
  const int start = offs[wid];
  const int c = cnt[wid];
  float ax = 0.f, ay = 0.f;
  int j = 0;
  for (; j + 1 < c; j += 2) {
    const int e0 = elist[start + j];
    const int e1 = elist[start + j + 1];
    const float2 a0 =
        *reinterpret_cast<const float2*>(edge_attr + (size_t)e0 * DIMC + lane * 2);
    const float2 a1 =
        *reinterpret_cast<const float2*>(edge_attr + (size_t)e1 * DIMC + lane * 2);
    ax += a0.x + a1.x;
    ay += a0.y + a1.y;
  }
  if (j < c) {
    const int e0 = elist[start + j];
    const float2 a0 =
        *reinterpret_cast<const float2*>(edge_attr + (size_t)e0 * DIMC + lane * 2);
    ax += a0.x;
    ay += a0.y;
  }
  const float inv = 1.0f / fmaxf((float)c, 1.0f);
  const unsigned packed =
      ((unsigned)f2bf(ay * inv) << 16) | (unsigned)f2bf(ax * inv);
  reinterpret_cast<unsigned*>(ve)[(size_t)wid * 64 + lane] = packed;
}

// ===========================================================================
// bf16 MFMA GEMM: H = relu(A' @ W^T + b) stored bf16, + fused BN-stat reduce.
//   MODE 0 (KTOT=384): A' cols 0-127 = x (f32), 128-255 = ve (bf16),
//                      256-383 = u[batch[row]] (f32)
//   MODE 1 (KTOT=128): A' = h_in (bf16). BN affine pre-folded into W/bias.
// Block: 64 rows x 128 cols, 256 thr = 4 waves; wave w = rows [w*16, w*16+16).
// K staged in 64-wide bf16 LDS chunks, T2 XOR swizzle (slot ^= row&7).
// ===========================================================================
template <int KTOT, int MODE>
__launch_bounds__(256, 2)
__global__ void gemm_mfma_kernel(const float* __restrict__ Af32,
                                 const u16* __restrict__ Abf,
                                 const float* __restrict__ u,
                                 const int* __restrict__ batch,
                                 const float* __restrict__ W,  // [128][KTOT] f32
                                 const float* __restrict__ bias,
                                 u16* __restrict__ Hout,  // [N][128] bf16
                                 float* __restrict__ stats,
                                 int N) {
  __shared__ u16 A_lds[64 * 64];
  __shared__ u16 W_lds[128 * 64];
  __shared__ float red[4][256];

  const int t = threadIdx.x;
  const int w = t >> 6;
  const int l = t & 63;
  const int row0 = blockIdx.x * 64;

  f32x4 acc[8];
#pragma unroll
  for (int cf = 0; cf < 8; ++cf) acc[cf] = {0.f, 0.f, 0.f, 0.f};

  const int nchunk = KTOT / 64;
  for (int ch = 0; ch < nchunk; ++ch) {
    // ---- stage A: 64 rows x 64 k bf16 = 512 x 16B slots, 2/thread ----
#pragma unroll
    for (int it = 0; it < 2; ++it) {
      const int s = t + it * 256;
      const int row = s >> 3;
      const int sl8 = s & 7;
      int grow = row0 + row;
      if (grow >= N) grow = N - 1;
      const int kg = ch * 64 + sl8 * 8;
      bf16x8 v;
      if constexpr (MODE == 0) {
        if (ch < 2) {
          const float4* p =
              reinterpret_cast<const float4*>(Af32 + (size_t)grow * DIMC + kg);
          v = pack8(p[0], p[1]);
        } else if (ch < 4) {
          v = *reinterpret_cast<const bf16x8*>(Abf + (size_t)grow * DIMC +
                                               (kg - 128));
        } else {
          const int g = batch[grow];
          const float4* p =
              reinterpret_cast<const float4*>(u + (size_t)g * DIMC + (kg - 256));
          v = pack8(p[0], p[1]);
        }
      } else {
        v = *reinterpret_cast<const bf16x8*>(Abf + (size_t)grow * DIMC + kg);
      }
      *reinterpret_cast<bf16x8*>(&A_lds[row * 64 + ((sl8 ^ (row & 7)) * 8)]) = v;
    }
    // ---- stage W: 128 rows x 64 k bf16 = 1024 slots, 4/thread ----
#pragma unroll
    for (int it = 0; it < 4; ++it) {
      const int s = t + it * 256;
      const int o = s >> 3;
      const int sl8 = s & 7;
      const float4* p =
          reinterpret_cast<const float4*>(W + (size_t)o * KTOT + ch * 64 + sl8 * 8);
      bf16x8 v = pack8(p[0], p[1]);
      *reinterpret_cast<bf16x8*>(&W_lds[o * 64 + ((sl8 ^ (o & 7)) * 8)]) = v;
    }
    __syncthreads();
    // ---- MFMA: 2 k-steps x 8 col-frags ----
#pragma unroll
    for (int ks = 0; ks < 2; ++ks) {
      const int arow = w * 16 + (l & 15);
      const int asl = ks * 4 + (l >> 4);
      const bf16x8 af = *reinterpret_cast<const bf16x8*>(
          &A_lds[arow * 64 + ((asl ^ (arow & 7)) * 8)]);
#pragma unroll
      for (int cf = 0; cf < 8; ++cf) {
        const int o = cf * 16 + (l & 15);
        const bf16x8 bfv = *reinterpret_cast<const bf16x8*>(
            &W_lds[o * 64 + ((asl ^ (o & 7)) * 8)]);
        acc[cf] =
            __builtin_amdgcn_mfma_f32_16x16x32_bf16(af, bfv, acc[cf], 0, 0, 0);
      }
    }
    __syncthreads();
  }

  // ---- epilogue: bias + relu + bf16 store + BN stats ----
  const int cbase = l & 15;
  const int rgrp = l >> 4;
#pragma unroll
  for (int cf = 0; cf < 8; ++cf) {
    const int col = cf * 16 + cbase;
    const float bv = bias[col];
    float s1 = 0.f, s2 = 0.f;
#pragma unroll
    for (int r = 0; r < 4; ++r) {
      const int grow = row0 + w * 16 + rgrp * 4 + r;
      const float vv = fmaxf(acc[cf][r] + bv, 0.f);
      if (grow < N) {
        Hout[(size_t)grow * DIMC + col] = f2bf(vv);
        s1 += vv;
        s2 += vv * vv;
      }
    }
    s1 += __shfl_xor(s1, 16, 64);
    s1 += __shfl_xor(s1, 32, 64);
    s2 += __shfl_xor(s2, 16, 64);
    s2 += __shfl_xor(s2, 32, 64);
    if (l < 16) {
      red[w][col] = s1;
      red[w][128 + col] = s2;
    }
  }
  __syncthreads();
  if (t < 128) {
    const float a = red[0][t] + red[1][t] + red[2][t] + red[3][t];
    const float b =
        red[0][128 + t] + red[1][128 + t] + red[2][128 + t] + red[3][128 + t];
    atomicAdd(&stats[t], a);
    atomicAdd(&stats[DIMC + t], b);
  }
}

// --- finalize BN stats -> per-column scale/shift ---------------------------
__global__ void finalize_stats_kernel(const float* __restrict__ stats,
                                      const float* __restrict__ g,
                                      const float* __restrict__ beta,
                                      float* __restrict__ scale,
                                      float* __restrict__ shift, float invN) {
  const int c = threadIdx.x;
  const float m = stats[c] * invN;
  float v = stats[DIMC + c] * invN - m * m;
  v = fmaxf(v, 0.f);
  const float sc = g[c] * rsqrtf(v + BN_EPS);
  scale[c] = sc;
  shift[c] = beta[c] - m * sc;
}

// --- fold BN affine of previous layer into next layer's weights ------------
// Wp[o,k] = W[o,k]*scale[k];  bp[o] = b[o] + sum_k W[o,k]*shift[k]
__global__ void fold_bn_kernel(const float* __restrict__ W,
                               const float* __restrict__ b,
                               const float* __restrict__ scale,
                               const float* __restrict__ shift,
                               float* __restrict__ Wp, float* __restrict__ bp) {
  __shared__ float sh[128];
  const int o = blockIdx.x;
  const int k = threadIdx.x;
  const float wv = W[(size_t)o * DIMC + k];
  Wp[(size_t)o * DIMC + k] = wv * scale[k];
  sh[k] = wv * shift[k];
  __syncthreads();
  for (int off = 64; off > 0; off >>= 1) {
    if (k < off) sh[k] += sh[k + off];
    __syncthreads();
  }
  if (k == 0) bp[o] = b[o] + sh[0];
}

// --- final: out = BN2 affine applied to h2 (bf16 -> fp32) ------------------
__global__ void final_affine_kernel(const u16* __restrict__ h,
                                    const float* __restrict__ scale,
                                    const float* __restrict__ shift,
                                    float* __restrict__ out, int nvec4) {
  int i = blockIdx.x * blockDim.x + threadIdx.x;
  const int stride = gridDim.x * blockDim.x;
  for (; i < nvec4; i += stride) {
    const int c = (i & 31) * 4;
    const ushort4 hv = reinterpret_cast<const ushort4*>(h)[i];
    const float4 sc = *reinterpret_cast<const float4*>(scale + c);
    const float4 sh = *reinterpret_cast<const float4*>(shift + c);
    reinterpret_cast<float4*>(out)[i] =
        make_float4(bf2f(hv.x) * sc.x + sh.x, bf2f(hv.y) * sc.y + sh.y,
                    bf2f(hv.z) * sc.z + sh.z, bf2f(hv.w) * sc.w + sh.w);
  }
}

// ---------------------------------------------------------------------------
extern "C" void kernel_launch(void* const* d_in, const int* in_sizes, int n_in,
                              void* d_out, int out_size, void* d_ws,
                              size_t ws_size, hipStream_t stream) {
  const float* x = (const float*)d_in[0];
  const int* edge_index = (const int*)d_in[1];  // row 0 = src
  const float* u = (const float*)d_in[3];
  const float* edge_attr = (const float*)d_in[2];
  const int* batch = (const int*)d_in[4];
  const float* W0 = (const float*)d_in[5];
  const float* b0 = (const float*)d_in[6];
  const float* W1 = (const float*)d_in[7];
  const float* b1 = (const float*)d_in[8];
  const float* W2 = (const float*)d_in[9];
  const float* b2 = (const float*)d_in[10];
  const float* g0 = (const float*)d_in[11];
  const float* be0 = (const float*)d_in[12];
  const float* g1 = (const float*)d_in[13];
  const float* be1 = (const float*)d_in[14];
  const float* g2 = (const float*)d_in[15];
  const float* be2 = (const float*)d_in[16];

  const int N = in_sizes[0] / DIMC;  // 50000
  const int E = in_sizes[2] / DIMC;  // 600000
  const int SCAN_BLOCKS = 256;       // covers up to 65536 nodes

  // ---- workspace carve-out (64B-aligned regions) ----
  uintptr_t p = (uintptr_t)d_ws;
  auto take = [&p](size_t bytes) {
    p = (p + 63) & ~(uintptr_t)63;
    uintptr_t r = p;
    p += bytes;
    return r;
  };
  u16* ve = (u16*)take((size_t)N * DIMC * 2);
  u16* h0 = (u16*)take((size_t)N * DIMC * 2);
  u16* h1 = (u16*)take((size_t)N * DIMC * 2);
  u16* h2 = (u16*)take((size_t)N * DIMC * 2);
  int* cnt = (int*)take((size_t)N * 4);
  int* offs = (int*)take((size_t)(N + 1) * 4);
  int* cursor = (int*)take((size_t)N * 4);
  int* elist = (int*)take((size_t)E * 4);
  int* bsums = (int*)take((size_t)SCAN_BLOCKS * 4);
  float* stats = (float*)take(6 * DIMC * 4);
  float* scsh = (float*)take(6 * DIMC * 4);
  float* W1p = (float*)take((size_t)DIMC * DIMC * 4);
  float* b1p = (float*)take(DIMC * 4);
  float* W2p = (float*)take((size_t)DIMC * DIMC * 4);
  float* b2p = (float*)take(DIMC * 4);

  hipMemsetAsync(cnt, 0, N * sizeof(int), stream);
  hipMemsetAsync(stats, 0, 6 * DIMC * sizeof(float), stream);

  // 1) CSR build + gather-mean (bf16 out)
  hist_kernel<<<512, 256, 0, stream>>>(edge_index, cnt, E);
  scan_pass_a<<<SCAN_BLOCKS, 256, 0, stream>>>(cnt, bsums, N);
  scan_pass_b<<<1, 256, 0, stream>>>(bsums);
  scan_pass_c<<<SCAN_BLOCKS, 256, 0, stream>>>(cnt, bsums, offs, cursor, N);
  bucket_kernel<<<512, 256, 0, stream>>>(edge_index, cursor, elist, E);
  gather_mean_kernel<<<(N * 64 + 255) / 256, 256, 0, stream>>>(
      edge_attr, elist, offs, cnt, ve, N);

  const int gblocks = (N + 63) / 64;
  const float invN = 1.0f / (float)N;

  // 2) layer 0: bf16 MFMA GEMM over [x | ve | u[batch]]
  gemm_mfma_kernel<3 * DIMC, 0><<<gblocks, 256, 0, stream>>>(
      x, ve, u, batch, W0, b0, h0, stats, N);
  finalize_stats_kernel<<<1, DIMC, 0, stream>>>(stats, g0, be0, scsh,
                                                scsh + DIMC, invN);
  fold_bn_kernel<<<DIMC, DIMC, 0, stream>>>(W1, b1, scsh, scsh + DIMC, W1p,
                                            b1p);

  // 3) layer 1: pure bf16 GEMM (BN0 folded into W1p/b1p)
  gemm_mfma_kernel<DIMC, 1><<<gblocks, 256, 0, stream>>>(
      nullptr, h0, nullptr, nullptr, W1p, b1p, h1, stats + 2 * DIMC, N);
  finalize_stats_kernel<<<1, DIMC, 0, stream>>>(stats + 2 * DIMC, g1, be1,
                                                scsh + 2 * DIMC,
                                                scsh + 3 * DIMC, invN);
  fold_bn_kernel<<<DIMC, DIMC, 0, stream>>>(W2, b2, scsh + 2 * DIMC,
                                            scsh + 3 * DIMC, W2p, b2p);

  // 4) layer 2
  gemm_mfma_kernel<DIMC, 1><<<gblocks, 256, 0, stream>>>(
      nullptr, h1, nullptr, nullptr, W2p, b2p, h2, stats + 4 * DIMC, N);
  finalize_stats_kernel<<<1, DIMC, 0, stream>>>(stats + 4 * DIMC, g2, be2,
                                                scsh + 4 * DIMC,
                                                scsh + 5 * DIMC, invN);

  // 5) apply BN2 -> fp32 output
  final_affine_kernel<<<2048, 256, 0, stream>>>(
      h2, scsh + 4 * DIMC, scsh + 5 * DIMC, (float*)d_out, (N * DIMC) / 4);
}